// Round 14
// baseline (225.501 us; speedup 1.0000x reference)
//
#include <hip/hip_runtime.h>

// out[r,f] = bias[f] + sum_{i: rows[i]==r} value[i] * weight[cols[i], f]
// R22 pipeline (2 kernels + memset): memset counts -> k_bin_fixed (CH=8192,
// vectorized loads, fixed-stride slots + spill) -> k_spmm13 (= spmm12 +
// NON-TEMPORAL weight loads (L1 bypass) + 6-wide batch (4->6 in-flight)).
// Consumer ledger: spmm5/9 (LDS acc, 3 phases) 60us; spmm12 (reg acc, 1
// phase) 60us; R14 dbuf 69; R16 CC=3072 69; R17 8-wide 69 (VGPR spill);
// R18 per-element flush 96. Six variants pinned at ~60 => the weight
// gather stream IS the floor; this round attacks the gather path itself
// (L1 allocation overhead + MLP depth). If null -> L2-delivery-bound,
// roofline.
// Front-end ledger: R9/R11 LDS fp-atomic accumulate 1310us; R15 cursor
// padding null; CH=4096 write fragmentation fixed by CH=8192 (~36us).
//
// pair pack (u64): val[63:32] | fine[29:20] | lr[19:13] | col[12:0]

#define NBF 1024
#define DMAX 128     // lr 7 bits => d <= 128 (n <= 131072)
#define CH 8192      // binning chunk (8/thread)
#define CC 4608      // consumer sort chunk (9/thread; >= max bucket size)
#define SP_T 512

typedef float __attribute__((ext_vector_type(4))) f32x4;
__device__ __forceinline__ f32x4 ldnt4(const float* p) {
    return __builtin_nontemporal_load((const f32x4*)p);
}

__global__ __launch_bounds__(1024) void k_bin_fixed(const int* __restrict__ rows,
        const int* __restrict__ cols, const float* __restrict__ vals, int nnz,
        unsigned M, int S, int d, int slots, int* __restrict__ cntF,
        unsigned long long* __restrict__ pairs1, int* __restrict__ ovfCnt,
        unsigned long long* __restrict__ ovf) {
    __shared__ unsigned long long stage[CH];       // 64 KB
    __shared__ int histF[NBF], scF[NBF], adjF[NBF];// 12 KB
    __shared__ int wsum[16];
    int t = threadIdx.x, lane = t & 63, wv = t >> 6;
    long long base = (long long)blockIdx.x * CH;
    int count = (int)min((long long)CH, (long long)nnz - base);
    histF[t] = 0;
    __syncthreads();
    int f8[8], rk8[8];
    unsigned long long pk8[8];
    if (count == CH) {
        const int4*   r4 = (const int4*)(rows + base);
        const int4*   c4 = (const int4*)(cols + base);
        const float4* v4 = (const float4*)(vals + base);
        int4 ra = r4[t * 2], rb = r4[t * 2 + 1];
        int4 ca = c4[t * 2], cb = c4[t * 2 + 1];
        float4 va = v4[t * 2], vb = v4[t * 2 + 1];
        int   rr[8] = {ra.x, ra.y, ra.z, ra.w, rb.x, rb.y, rb.z, rb.w};
        int   cc[8] = {ca.x, ca.y, ca.z, ca.w, cb.x, cb.y, cb.z, cb.w};
        float vv[8] = {va.x, va.y, va.z, va.w, vb.x, vb.y, vb.z, vb.w};
#pragma unroll
        for (int k = 0; k < 8; ++k) {
            unsigned r = (unsigned)rr[k];
            int f = (int)(((unsigned long long)r * M) >> S);
            int lr = (int)r - f * d;
            f8[k] = f;
            rk8[k] = atomicAdd(&histF[f], 1);
            pk8[k] = ((unsigned long long)__float_as_uint(vv[k]) << 32) |
                     ((unsigned)f << 20) | ((unsigned)lr << 13) | (unsigned)cc[k];
        }
    } else {
#pragma unroll
        for (int k = 0; k < 8; ++k) {
            int i = t + (k << 10);
            f8[k] = -1;
            if (i < count) {
                unsigned r = (unsigned)rows[base + i];
                int c = cols[base + i];
                float vv = vals[base + i];
                int f = (int)(((unsigned long long)r * M) >> S);
                int lr = (int)r - f * d;
                f8[k] = f;
                rk8[k] = atomicAdd(&histF[f], 1);
                pk8[k] = ((unsigned long long)__float_as_uint(vv) << 32) |
                         ((unsigned)f << 20) | ((unsigned)lr << 13) | (unsigned)c;
            }
        }
    }
    __syncthreads();
    int v = histF[t], x = v;
#pragma unroll
    for (int off = 1; off < 64; off <<= 1) {
        int y = __shfl_up(x, off, 64);
        if (lane >= off) x += y;
    }
    if (lane == 63) wsum[wv] = x;
    __syncthreads();
    if (t < 16) {
        int s = wsum[t], xs = s;
#pragma unroll
        for (int off = 1; off < 16; off <<= 1) {
            int y = __shfl_up(xs, off, 16);
            if (t >= off) xs += y;
        }
        wsum[t] = xs - s;
    }
    __syncthreads();
    int incl = x + wsum[wv];
    scF[t] = incl;
    if (v > 0) {
        int g = atomicAdd(&cntF[t], v);
        adjF[t] = t * slots + g - (incl - v);
    }
    __syncthreads();
#pragma unroll
    for (int k = 0; k < 8; ++k)
        if (f8[k] >= 0) stage[(scF[f8[k]] - histF[f8[k]]) + rk8[k]] = pk8[k];
    __syncthreads();
    for (int i = t; i < count; i += 1024) {
        unsigned long long p = stage[i];
        int f = (int)((p >> 20) & 1023);
        int dest = adjF[f] + i;
        if (dest < (f + 1) * slots) pairs1[dest] = p;
        else ovf[atomicAdd(ovfCnt, 1)] = p;
    }
}

// Consumer v6: register accumulator + whole-bucket sort + nt weight loads +
// 6-wide batch. LDS: stage 36.9KB + hist 1KB -> 4 blocks/CU. Rank keeps
// packed (rk<<7)|lr; scatter re-reads pairs from L2 (VGPR discipline).
__global__ __launch_bounds__(SP_T, 8) void k_spmm13(
        const unsigned long long* __restrict__ pairs, const int* __restrict__ cntF,
        const int* __restrict__ ovfCnt, const unsigned long long* __restrict__ ovf,
        const float* __restrict__ weight, const float* __restrict__ bias,
        float* __restrict__ out, int d, int n, int slots) {
    __shared__ unsigned long long stage[CC];   // 36.9 KB
    __shared__ int histR[DMAX], scR[DMAX];     // 1 KB
    int b = blockIdx.x, t = threadIdx.x;
    int row0 = b * d;
    if (row0 >= n) return;
    int nrows = min(d, n - row0);
    long long sbase = (long long)b * slots;
    int cnt = cntF[b];
    if (cnt > slots) cnt = slots;
    if (cnt < 0) cnt = 0;

    int g = t >> 4, fq = t & 15;
    const float* wbase = weight + (fq << 2);
    float4 a0 = {0,0,0,0}, a1 = {0,0,0,0}, a2 = {0,0,0,0}, a3 = {0,0,0,0};

    for (int cb = 0; cb < cnt; cb += CC) {
        int ccnt = min(CC, cnt - cb);
        if (t < DMAX) histR[t] = 0;
        __syncthreads();
        int pr9[9];  // (rk<<7)|lr, or -1
#pragma unroll
        for (int k = 0; k < 9; ++k) {
            int i = t + (k << 9);
            pr9[k] = -1;
            if (i < ccnt) {
                unsigned long long p = pairs[sbase + cb + i];
                int lr = (int)((p >> 13) & 127);
                int rk = atomicAdd(&histR[lr], 1);
                pr9[k] = (rk << 7) | lr;
            }
        }
        __syncthreads();
        if (t < DMAX) {
            int v = histR[t], x = v;
            int lane = t & 63;
#pragma unroll
            for (int off = 1; off < 64; off <<= 1) {
                int y = __shfl_up(x, off, 64);
                if (lane >= off) x += y;
            }
            scR[t] = x;
        }
        __syncthreads();
        if (t >= 64 && t < DMAX) scR[t] += scR[63];
        __syncthreads();
#pragma unroll
        for (int k = 0; k < 9; ++k) {
            if (pr9[k] >= 0) {
                int i = t + (k << 9);
                int lr = pr9[k] & 127, rk = pr9[k] >> 7;
                stage[(scR[lr] - histR[lr]) + rk] = pairs[sbase + cb + i];
            }
        }
        __syncthreads();

#define FMA1(V, W, A)                                                         \
        A.x = fmaf(V, W.x, A.x); A.y = fmaf(V, W.y, A.y);                     \
        A.z = fmaf(V, W.z, A.z); A.w = fmaf(V, W.w, A.w);
#define CONSUME_ROW(K)                                                        \
        {                                                                     \
            int r = g + (K << 5);                                             \
            if (r < nrows) {                                                  \
                int e = scR[r], s = e - histR[r];                             \
                float4 a = {0,0,0,0};                                         \
                int j = s;                                                    \
                for (; j + 6 <= e; j += 6) {                                  \
                    unsigned long long p0 = stage[j + 0];                     \
                    unsigned long long p1 = stage[j + 1];                     \
                    unsigned long long p2 = stage[j + 2];                     \
                    unsigned long long p3 = stage[j + 3];                     \
                    unsigned long long p4 = stage[j + 4];                     \
                    unsigned long long p5 = stage[j + 5];                     \
                    f32x4 w0 = ldnt4(wbase + ((int)(p0 & 8191) << 6));        \
                    f32x4 w1 = ldnt4(wbase + ((int)(p1 & 8191) << 6));        \
                    f32x4 w2 = ldnt4(wbase + ((int)(p2 & 8191) << 6));        \
                    f32x4 w3 = ldnt4(wbase + ((int)(p3 & 8191) << 6));        \
                    f32x4 w4 = ldnt4(wbase + ((int)(p4 & 8191) << 6));        \
                    f32x4 w5 = ldnt4(wbase + ((int)(p5 & 8191) << 6));        \
                    float v0 = __uint_as_float((unsigned)(p0 >> 32));         \
                    float v1 = __uint_as_float((unsigned)(p1 >> 32));         \
                    float v2 = __uint_as_float((unsigned)(p2 >> 32));         \
                    float v3 = __uint_as_float((unsigned)(p3 >> 32));         \
                    float v4 = __uint_as_float((unsigned)(p4 >> 32));         \
                    float v5 = __uint_as_float((unsigned)(p5 >> 32));         \
                    FMA1(v0, w0, a) FMA1(v1, w1, a) FMA1(v2, w2, a)           \
                    FMA1(v3, w3, a) FMA1(v4, w4, a) FMA1(v5, w5, a)           \
                }                                                             \
                for (; j + 2 <= e; j += 2) {                                  \
                    unsigned long long p0 = stage[j + 0];                     \
                    unsigned long long p1 = stage[j + 1];                     \
                    f32x4 w0 = ldnt4(wbase + ((int)(p0 & 8191) << 6));        \
                    f32x4 w1 = ldnt4(wbase + ((int)(p1 & 8191) << 6));        \
                    float v0 = __uint_as_float((unsigned)(p0 >> 32));         \
                    float v1 = __uint_as_float((unsigned)(p1 >> 32));         \
                    FMA1(v0, w0, a) FMA1(v1, w1, a)                           \
                }                                                             \
                if (j < e) {                                                  \
                    unsigned long long p = stage[j];                          \
                    f32x4 w = ldnt4(wbase + ((int)(p & 8191) << 6));          \
                    float vv = __uint_as_float((unsigned)(p >> 32));          \
                    FMA1(vv, w, a)                                            \
                }                                                             \
                a##K.x += a.x; a##K.y += a.y; a##K.z += a.z; a##K.w += a.w;   \
            }                                                                 \
        }
        CONSUME_ROW(0) CONSUME_ROW(1) CONSUME_ROW(2) CONSUME_ROW(3)
#undef CONSUME_ROW
        __syncthreads();
    }

    // overflow (spilled pairs): statistically empty for uniform rows.
    int oc = *ovfCnt;
    if (oc > 0) {
        for (int i = 0; i < oc; ++i) {
            unsigned long long p = ovf[i];
            if ((int)((p >> 20) & 1023) == b) {
                int lr = (int)((p >> 13) & 127);
                if ((lr & 31) == g) {
                    int cc = (int)(p & 8191);
                    float vv = __uint_as_float((unsigned)(p >> 32));
                    f32x4 w = ldnt4(wbase + (cc << 6));
                    int k = lr >> 5;
                    if (k == 0)      { FMA1(vv, w, a0) }
                    else if (k == 1) { FMA1(vv, w, a1) }
                    else if (k == 2) { FMA1(vv, w, a2) }
                    else             { FMA1(vv, w, a3) }
                }
            }
        }
    }
#undef FMA1

    // epilogue: each group writes its owned rows from registers (+bias).
    float4 b4 = *(const float4*)(bias + (fq << 2));
#define WRITE_ROW(K)                                                          \
    {                                                                         \
        int r = g + (K << 5);                                                 \
        if (r < nrows) {                                                      \
            float4 o;                                                         \
            o.x = a##K.x + b4.x; o.y = a##K.y + b4.y;                         \
            o.z = a##K.z + b4.z; o.w = a##K.w + b4.w;                         \
            *(float4*)(out + (((long long)(row0 + r)) << 6) + (fq << 2)) = o; \
        }                                                                     \
    }
    WRITE_ROW(0) WRITE_ROW(1) WRITE_ROW(2) WRITE_ROW(3)
#undef WRITE_ROW
}

extern "C" void kernel_launch(void* const* d_in, const int* in_sizes, int n_in,
                              void* d_out, int out_size, void* d_ws, size_t ws_size,
                              hipStream_t stream) {
    const int*   index  = (const int*)d_in[0];
    const float* value  = (const float*)d_in[1];
    const float* weight = (const float*)d_in[3];
    const float* bias   = (const float*)d_in[4];
    float*       out    = (float*)d_out;

    int nnz = in_sizes[0] / 2;
    int n   = out_size / 64;
    const int* rows = index;
    const int* cols = index + nnz;

    int d = (n + NBF - 1) / NBF;  // 98 for n=100000 (<= DMAX)
    unsigned M = 0;
    int S = 0;
    for (S = 20; S <= 40; ++S) {
        unsigned long long m = ((1ull << S) + (unsigned)d - 1) / (unsigned)d;
        unsigned long long e = m * (unsigned long long)d - (1ull << S);
        if (m <= 0xffffffffull && e * (unsigned long long)(n > 0 ? n - 1 : 0) < (1ull << S)) {
            M = (unsigned)m;
            break;
        }
    }

    int nChunks = (nnz + CH - 1) / CH;
    char* ws = (char*)d_ws;
    int* cntF   = (int*)ws;                   // 4 KB (per-bucket counts)
    int* ovfCnt = (int*)(ws + 4096);
    unsigned long long* pairsS = (unsigned long long*)(ws + (128 << 10));

    size_t szOvf = (((size_t)nnz * 8) + 255) & ~(size_t)255;
    size_t availS = (ws_size > (128 << 10) + szOvf) ? (ws_size - (128 << 10) - szOvf) : 0;
    long long slotsL = (long long)(availS / ((size_t)NBF * 8));
    int slots = (int)(slotsL > 6144 ? 6144 : slotsL);
    if (slots > 64) slots &= ~63;
    if (slots < 1) slots = 1;
    unsigned long long* ovf = (unsigned long long*)(ws + (128 << 10) + (size_t)slots * NBF * 8);

    hipMemsetAsync(ws, 0, 8192, stream);  // cntF (4KB) + ovfCnt
    k_bin_fixed<<<nChunks, 1024, 0, stream>>>(rows, cols, value, nnz, M, S, d, slots,
                                              cntF, pairsS, ovfCnt, ovf);
    k_spmm13<<<NBF, SP_T, 0, stream>>>(pairsS, cntF, ovfCnt, ovf, weight, bias,
                                       out, d, n, slots);
}

// Round 15
// 169.441 us; speedup vs baseline: 1.3309x; 1.3309x over previous
//
#include <hip/hip_runtime.h>

// out[r,f] = bias[f] + sum_{i: rows[i]==r} value[i] * weight[cols[i], f]
// R23 pipeline (2 kernels + memset): memset counts -> k_bin_fixed (CH=8192,
// vectorized loads, fixed-stride slots + spill) -> k_spmm14 (= spmm12 with
// 6-wide batch, PLAIN cached loads — isolates the batch-depth variable).
// R22 post-mortem: nontemporal weight loads defeated L2 caching of the
// 1.25MB weight (FETCH 30->181MB, HBM 2TB/s, 124us). Proves the 60us
// consumer runs at ~97% cache hit (~17 TB/s delivery). nt on reused data =
// anti-lesson. 6-wide didn't spill (VGPR 32) but was confounded -> R23
// tests it clean.
// Consumer ledger: spmm5/9 (LDS acc) 60us; spmm12 (reg acc, 1 phase) 60us;
// R14 dbuf 69; R16 CC=3072 69; R17 8-wide 69 (spill); R18 flush-branch 96;
// R22 nt 124. If R23 lands ~60 again -> cache-delivery-bound, roofline.
// Front-end ledger: R9/R11 LDS fp-atomic accumulate 1310us; R15 cursor
// padding null; CH=4096 write fragmentation fixed by CH=8192 (~36us).
//
// pair pack (u64): val[63:32] | fine[29:20] | lr[19:13] | col[12:0]

#define NBF 1024
#define DMAX 128     // lr 7 bits => d <= 128 (n <= 131072)
#define CH 8192      // binning chunk (8/thread)
#define CC 4608      // consumer sort chunk (9/thread; >= max bucket size)
#define SP_T 512

__global__ __launch_bounds__(1024) void k_bin_fixed(const int* __restrict__ rows,
        const int* __restrict__ cols, const float* __restrict__ vals, int nnz,
        unsigned M, int S, int d, int slots, int* __restrict__ cntF,
        unsigned long long* __restrict__ pairs1, int* __restrict__ ovfCnt,
        unsigned long long* __restrict__ ovf) {
    __shared__ unsigned long long stage[CH];       // 64 KB
    __shared__ int histF[NBF], scF[NBF], adjF[NBF];// 12 KB
    __shared__ int wsum[16];
    int t = threadIdx.x, lane = t & 63, wv = t >> 6;
    long long base = (long long)blockIdx.x * CH;
    int count = (int)min((long long)CH, (long long)nnz - base);
    histF[t] = 0;
    __syncthreads();
    int f8[8], rk8[8];
    unsigned long long pk8[8];
    if (count == CH) {
        const int4*   r4 = (const int4*)(rows + base);
        const int4*   c4 = (const int4*)(cols + base);
        const float4* v4 = (const float4*)(vals + base);
        int4 ra = r4[t * 2], rb = r4[t * 2 + 1];
        int4 ca = c4[t * 2], cb = c4[t * 2 + 1];
        float4 va = v4[t * 2], vb = v4[t * 2 + 1];
        int   rr[8] = {ra.x, ra.y, ra.z, ra.w, rb.x, rb.y, rb.z, rb.w};
        int   cc[8] = {ca.x, ca.y, ca.z, ca.w, cb.x, cb.y, cb.z, cb.w};
        float vv[8] = {va.x, va.y, va.z, va.w, vb.x, vb.y, vb.z, vb.w};
#pragma unroll
        for (int k = 0; k < 8; ++k) {
            unsigned r = (unsigned)rr[k];
            int f = (int)(((unsigned long long)r * M) >> S);
            int lr = (int)r - f * d;
            f8[k] = f;
            rk8[k] = atomicAdd(&histF[f], 1);
            pk8[k] = ((unsigned long long)__float_as_uint(vv[k]) << 32) |
                     ((unsigned)f << 20) | ((unsigned)lr << 13) | (unsigned)cc[k];
        }
    } else {
#pragma unroll
        for (int k = 0; k < 8; ++k) {
            int i = t + (k << 10);
            f8[k] = -1;
            if (i < count) {
                unsigned r = (unsigned)rows[base + i];
                int c = cols[base + i];
                float vv = vals[base + i];
                int f = (int)(((unsigned long long)r * M) >> S);
                int lr = (int)r - f * d;
                f8[k] = f;
                rk8[k] = atomicAdd(&histF[f], 1);
                pk8[k] = ((unsigned long long)__float_as_uint(vv) << 32) |
                         ((unsigned)f << 20) | ((unsigned)lr << 13) | (unsigned)c;
            }
        }
    }
    __syncthreads();
    int v = histF[t], x = v;
#pragma unroll
    for (int off = 1; off < 64; off <<= 1) {
        int y = __shfl_up(x, off, 64);
        if (lane >= off) x += y;
    }
    if (lane == 63) wsum[wv] = x;
    __syncthreads();
    if (t < 16) {
        int s = wsum[t], xs = s;
#pragma unroll
        for (int off = 1; off < 16; off <<= 1) {
            int y = __shfl_up(xs, off, 16);
            if (t >= off) xs += y;
        }
        wsum[t] = xs - s;
    }
    __syncthreads();
    int incl = x + wsum[wv];
    scF[t] = incl;
    if (v > 0) {
        int g = atomicAdd(&cntF[t], v);
        adjF[t] = t * slots + g - (incl - v);
    }
    __syncthreads();
#pragma unroll
    for (int k = 0; k < 8; ++k)
        if (f8[k] >= 0) stage[(scF[f8[k]] - histF[f8[k]]) + rk8[k]] = pk8[k];
    __syncthreads();
    for (int i = t; i < count; i += 1024) {
        unsigned long long p = stage[i];
        int f = (int)((p >> 20) & 1023);
        int dest = adjF[f] + i;
        if (dest < (f + 1) * slots) pairs1[dest] = p;
        else ovf[atomicAdd(ovfCnt, 1)] = p;
    }
}

// Consumer v7: register accumulator + whole-bucket sort + 6-wide batch with
// PLAIN cached loads. LDS: stage 36.9KB + hist 1KB -> 4 blocks/CU.
__global__ __launch_bounds__(SP_T, 8) void k_spmm14(
        const unsigned long long* __restrict__ pairs, const int* __restrict__ cntF,
        const int* __restrict__ ovfCnt, const unsigned long long* __restrict__ ovf,
        const float* __restrict__ weight, const float* __restrict__ bias,
        float* __restrict__ out, int d, int n, int slots) {
    __shared__ unsigned long long stage[CC];   // 36.9 KB
    __shared__ int histR[DMAX], scR[DMAX];     // 1 KB
    int b = blockIdx.x, t = threadIdx.x;
    int row0 = b * d;
    if (row0 >= n) return;
    int nrows = min(d, n - row0);
    long long sbase = (long long)b * slots;
    int cnt = cntF[b];
    if (cnt > slots) cnt = slots;
    if (cnt < 0) cnt = 0;

    int g = t >> 4, fq = t & 15;
    const float* wbase = weight + (fq << 2);
    float4 a0 = {0,0,0,0}, a1 = {0,0,0,0}, a2 = {0,0,0,0}, a3 = {0,0,0,0};

    for (int cb = 0; cb < cnt; cb += CC) {
        int ccnt = min(CC, cnt - cb);
        if (t < DMAX) histR[t] = 0;
        __syncthreads();
        int pr9[9];  // (rk<<7)|lr, or -1
#pragma unroll
        for (int k = 0; k < 9; ++k) {
            int i = t + (k << 9);
            pr9[k] = -1;
            if (i < ccnt) {
                unsigned long long p = pairs[sbase + cb + i];
                int lr = (int)((p >> 13) & 127);
                int rk = atomicAdd(&histR[lr], 1);
                pr9[k] = (rk << 7) | lr;
            }
        }
        __syncthreads();
        if (t < DMAX) {
            int v = histR[t], x = v;
            int lane = t & 63;
#pragma unroll
            for (int off = 1; off < 64; off <<= 1) {
                int y = __shfl_up(x, off, 64);
                if (lane >= off) x += y;
            }
            scR[t] = x;
        }
        __syncthreads();
        if (t >= 64 && t < DMAX) scR[t] += scR[63];
        __syncthreads();
#pragma unroll
        for (int k = 0; k < 9; ++k) {
            if (pr9[k] >= 0) {
                int i = t + (k << 9);
                int lr = pr9[k] & 127, rk = pr9[k] >> 7;
                stage[(scR[lr] - histR[lr]) + rk] = pairs[sbase + cb + i];
            }
        }
        __syncthreads();

#define FMA1(V, W, A)                                                         \
        A.x = fmaf(V, W.x, A.x); A.y = fmaf(V, W.y, A.y);                     \
        A.z = fmaf(V, W.z, A.z); A.w = fmaf(V, W.w, A.w);
#define CONSUME_ROW(K)                                                        \
        {                                                                     \
            int r = g + (K << 5);                                             \
            if (r < nrows) {                                                  \
                int e = scR[r], s = e - histR[r];                             \
                float4 a = {0,0,0,0};                                         \
                int j = s;                                                    \
                for (; j + 6 <= e; j += 6) {                                  \
                    unsigned long long p0 = stage[j + 0];                     \
                    unsigned long long p1 = stage[j + 1];                     \
                    unsigned long long p2 = stage[j + 2];                     \
                    unsigned long long p3 = stage[j + 3];                     \
                    unsigned long long p4 = stage[j + 4];                     \
                    unsigned long long p5 = stage[j + 5];                     \
                    const float4 w0 = *(const float4*)(wbase + ((int)(p0 & 8191) << 6)); \
                    const float4 w1 = *(const float4*)(wbase + ((int)(p1 & 8191) << 6)); \
                    const float4 w2 = *(const float4*)(wbase + ((int)(p2 & 8191) << 6)); \
                    const float4 w3 = *(const float4*)(wbase + ((int)(p3 & 8191) << 6)); \
                    const float4 w4 = *(const float4*)(wbase + ((int)(p4 & 8191) << 6)); \
                    const float4 w5 = *(const float4*)(wbase + ((int)(p5 & 8191) << 6)); \
                    float v0 = __uint_as_float((unsigned)(p0 >> 32));         \
                    float v1 = __uint_as_float((unsigned)(p1 >> 32));         \
                    float v2 = __uint_as_float((unsigned)(p2 >> 32));         \
                    float v3 = __uint_as_float((unsigned)(p3 >> 32));         \
                    float v4 = __uint_as_float((unsigned)(p4 >> 32));         \
                    float v5 = __uint_as_float((unsigned)(p5 >> 32));         \
                    FMA1(v0, w0, a) FMA1(v1, w1, a) FMA1(v2, w2, a)           \
                    FMA1(v3, w3, a) FMA1(v4, w4, a) FMA1(v5, w5, a)           \
                }                                                             \
                for (; j + 2 <= e; j += 2) {                                  \
                    unsigned long long p0 = stage[j + 0];                     \
                    unsigned long long p1 = stage[j + 1];                     \
                    const float4 w0 = *(const float4*)(wbase + ((int)(p0 & 8191) << 6)); \
                    const float4 w1 = *(const float4*)(wbase + ((int)(p1 & 8191) << 6)); \
                    float v0 = __uint_as_float((unsigned)(p0 >> 32));         \
                    float v1 = __uint_as_float((unsigned)(p1 >> 32));         \
                    FMA1(v0, w0, a) FMA1(v1, w1, a)                           \
                }                                                             \
                if (j < e) {                                                  \
                    unsigned long long p = stage[j];                          \
                    const float4 w = *(const float4*)(wbase + ((int)(p & 8191) << 6)); \
                    float vv = __uint_as_float((unsigned)(p >> 32));          \
                    FMA1(vv, w, a)                                            \
                }                                                             \
                a##K.x += a.x; a##K.y += a.y; a##K.z += a.z; a##K.w += a.w;   \
            }                                                                 \
        }
        CONSUME_ROW(0) CONSUME_ROW(1) CONSUME_ROW(2) CONSUME_ROW(3)
#undef CONSUME_ROW
        __syncthreads();
    }

    // overflow (spilled pairs): statistically empty for uniform rows.
    int oc = *ovfCnt;
    if (oc > 0) {
        for (int i = 0; i < oc; ++i) {
            unsigned long long p = ovf[i];
            if ((int)((p >> 20) & 1023) == b) {
                int lr = (int)((p >> 13) & 127);
                if ((lr & 31) == g) {
                    int cc = (int)(p & 8191);
                    float vv = __uint_as_float((unsigned)(p >> 32));
                    const float4 w = *(const float4*)(wbase + (cc << 6));
                    int k = lr >> 5;
                    if (k == 0)      { FMA1(vv, w, a0) }
                    else if (k == 1) { FMA1(vv, w, a1) }
                    else if (k == 2) { FMA1(vv, w, a2) }
                    else             { FMA1(vv, w, a3) }
                }
            }
        }
    }
#undef FMA1

    // epilogue: each group writes its owned rows from registers (+bias).
    float4 b4 = *(const float4*)(bias + (fq << 2));
#define WRITE_ROW(K)                                                          \
    {                                                                         \
        int r = g + (K << 5);                                                 \
        if (r < nrows) {                                                      \
            float4 o;                                                         \
            o.x = a##K.x + b4.x; o.y = a##K.y + b4.y;                         \
            o.z = a##K.z + b4.z; o.w = a##K.w + b4.w;                         \
            *(float4*)(out + (((long long)(row0 + r)) << 6) + (fq << 2)) = o; \
        }                                                                     \
    }
    WRITE_ROW(0) WRITE_ROW(1) WRITE_ROW(2) WRITE_ROW(3)
#undef WRITE_ROW
}

extern "C" void kernel_launch(void* const* d_in, const int* in_sizes, int n_in,
                              void* d_out, int out_size, void* d_ws, size_t ws_size,
                              hipStream_t stream) {
    const int*   index  = (const int*)d_in[0];
    const float* value  = (const float*)d_in[1];
    const float* weight = (const float*)d_in[3];
    const float* bias   = (const float*)d_in[4];
    float*       out    = (float*)d_out;

    int nnz = in_sizes[0] / 2;
    int n   = out_size / 64;
    const int* rows = index;
    const int* cols = index + nnz;

    int d = (n + NBF - 1) / NBF;  // 98 for n=100000 (<= DMAX)
    unsigned M = 0;
    int S = 0;
    for (S = 20; S <= 40; ++S) {
        unsigned long long m = ((1ull << S) + (unsigned)d - 1) / (unsigned)d;
        unsigned long long e = m * (unsigned long long)d - (1ull << S);
        if (m <= 0xffffffffull && e * (unsigned long long)(n > 0 ? n - 1 : 0) < (1ull << S)) {
            M = (unsigned)m;
            break;
        }
    }

    int nChunks = (nnz + CH - 1) / CH;
    char* ws = (char*)d_ws;
    int* cntF   = (int*)ws;                   // 4 KB (per-bucket counts)
    int* ovfCnt = (int*)(ws + 4096);
    unsigned long long* pairsS = (unsigned long long*)(ws + (128 << 10));

    size_t szOvf = (((size_t)nnz * 8) + 255) & ~(size_t)255;
    size_t availS = (ws_size > (128 << 10) + szOvf) ? (ws_size - (128 << 10) - szOvf) : 0;
    long long slotsL = (long long)(availS / ((size_t)NBF * 8));
    int slots = (int)(slotsL > 6144 ? 6144 : slotsL);
    if (slots > 64) slots &= ~63;
    if (slots < 1) slots = 1;
    unsigned long long* ovf = (unsigned long long*)(ws + (128 << 10) + (size_t)slots * NBF * 8);

    hipMemsetAsync(ws, 0, 8192, stream);  // cntF (4KB) + ovfCnt
    k_bin_fixed<<<nChunks, 1024, 0, stream>>>(rows, cols, value, nnz, M, S, d, slots,
                                              cntF, pairsS, ovfCnt, ovf);
    k_spmm14<<<NBF, SP_T, 0, stream>>>(pairsS, cntF, ovfCnt, ovf, weight, bias,
                                       out, d, n, slots);
}